// Round 1
// baseline (512.761 us; speedup 1.0000x reference)
//
#include <hip/hip_runtime.h>
#include <hip/hip_bf16.h>

// C[b,i] = 0.125 * sum_k LI[X[b,8,3]][k] * IL[i][k]
// M=1024, N=100000, K=64.  Write-bound (409.6 MB out); bf16 MFMA for compute.

typedef short short8 __attribute__((ext_vector_type(8)));
typedef float f32x4 __attribute__((ext_vector_type(4)));
typedef unsigned short ushort4v __attribute__((ext_vector_type(4)));

#define KDIM 64
#define LDSS 72   // padded LDS row stride in bf16 elems (144 B: 16B-aligned, 2-way bank alias only)

static __device__ __forceinline__ unsigned short f2bf(float f) {
    unsigned u = __float_as_uint(f);
    unsigned r = (u + 0x7fffu + ((u >> 16) & 1u)) >> 16;   // RNE
    return (unsigned short)r;
}

__global__ __launch_bounds__(256)
void fpmc_gemm(const int* __restrict__ X,
               const float* __restrict__ IL,
               const float* __restrict__ LI,
               float* __restrict__ out,
               int M, int N) {
    __shared__ unsigned short As[128 * LDSS];
    __shared__ unsigned short Bs[128 * LDSS];

    const int t  = threadIdx.x;
    const int m0 = blockIdx.y * 128;
    const int i0 = blockIdx.x * 128;

    // ---- stage A tile: gather LI rows via X, convert fp32->bf16 ----
    {
        const int rb = t >> 4;          // 0..15
        const int c  = (t & 15) * 4;    // 0..60 step 4
        #pragma unroll
        for (int it = 0; it < 8; ++it) {
            const int r = it * 16 + rb;                 // 0..127
            const int idx = X[(m0 + r) * 40 + 35];      // X[b, 8, 3]
            const float4 v = *(const float4*)(LI + (size_t)idx * KDIM + c);
            ushort4v p;
            p.x = f2bf(v.x); p.y = f2bf(v.y); p.z = f2bf(v.z); p.w = f2bf(v.w);
            *(ushort4v*)&As[r * LDSS + c] = p;
        }
    }
    // ---- stage B tile: IL rows i0..i0+127, convert fp32->bf16 ----
    {
        const int rb = t >> 4;
        const int c  = (t & 15) * 4;
        #pragma unroll
        for (int it = 0; it < 8; ++it) {
            const int r = it * 16 + rb;
            int gi = i0 + r;
            if (gi > N - 1) gi = N - 1;                 // clamp; stores guarded later
            const float4 v = *(const float4*)(IL + (size_t)gi * KDIM + c);
            ushort4v p;
            p.x = f2bf(v.x); p.y = f2bf(v.y); p.z = f2bf(v.z); p.w = f2bf(v.w);
            *(ushort4v*)&Bs[r * LDSS + c] = p;
        }
    }
    __syncthreads();

    // ---- compute: wave (w&1)->M half, (w>>1)->N half; 64x64 per wave ----
    const int w    = t >> 6;
    const int l    = t & 63;
    const int row  = l & 15;     // fragment row (m for A, n for B, col for C/D)
    const int quad = l >> 4;     // 0..3
    const int mw   = (w & 1) * 64;
    const int nw   = (w >> 1) * 64;

    f32x4 acc[4][4];
    #pragma unroll
    for (int mt = 0; mt < 4; ++mt)
        #pragma unroll
        for (int nt = 0; nt < 4; ++nt)
            acc[mt][nt] = (f32x4){0.f, 0.f, 0.f, 0.f};

    #pragma unroll
    for (int ks = 0; ks < KDIM; ks += 32) {
        short8 a[4], b[4];
        #pragma unroll
        for (int mt = 0; mt < 4; ++mt)
            a[mt] = *(const short8*)&As[(mw + mt * 16 + row) * LDSS + ks + quad * 8];
        #pragma unroll
        for (int nt = 0; nt < 4; ++nt)
            b[nt] = *(const short8*)&Bs[(nw + nt * 16 + row) * LDSS + ks + quad * 8];
        #pragma unroll
        for (int mt = 0; mt < 4; ++mt)
            #pragma unroll
            for (int nt = 0; nt < 4; ++nt)
                acc[mt][nt] = __builtin_amdgcn_mfma_f32_16x16x32_bf16(
                    a[mt], b[nt], acc[mt][nt], 0, 0, 0);
    }

    // ---- epilogue: C/D layout col=lane&15, row=quad*4+reg ----
    const float scale = 0.125f;   // 1/sqrt(64)
    #pragma unroll
    for (int mt = 0; mt < 4; ++mt) {
        #pragma unroll
        for (int reg = 0; reg < 4; ++reg) {
            const int m = m0 + mw + mt * 16 + quad * 4 + reg;
            float* orow = out + (size_t)m * N;
            #pragma unroll
            for (int nt = 0; nt < 4; ++nt) {
                const int n = i0 + nw + nt * 16 + row;
                if (n < N) orow[n] = acc[mt][nt][reg] * scale;
            }
        }
    }
}

extern "C" void kernel_launch(void* const* d_in, const int* in_sizes, int n_in,
                              void* d_out, int out_size, void* d_ws, size_t ws_size,
                              hipStream_t stream) {
    const int*   X  = (const int*)d_in[0];
    const float* IL = (const float*)d_in[1];
    const float* LI = (const float*)d_in[2];
    float* out = (float*)d_out;

    const int M = in_sizes[0] / 40;      // 1024
    const int N = in_sizes[1] / KDIM;    // 100000

    dim3 grid((N + 127) / 128, M / 128);
    fpmc_gemm<<<grid, dim3(256), 0, stream>>>(X, IL, LI, out, M, N);
}